// Round 11
// baseline (324.770 us; speedup 1.0000x reference)
//
#include <hip/hip_runtime.h>
#include <math.h>

#define HW 9216
#define Hh 96
#define Ww 96
#define PHW 9604   // 98*98 padded

typedef __attribute__((ext_vector_type(8))) short bh8;
typedef __attribute__((ext_vector_type(4))) short bh4;
typedef __attribute__((ext_vector_type(4))) float f32x4;
typedef __attribute__((ext_vector_type(2))) float f32x2;
typedef __attribute__((ext_vector_type(4))) int i32x4;
union bh8i { bh8 v; i32x4 i; };

__device__ __forceinline__ short f2bf(float f) {
    union { float f; unsigned u; } v; v.f = f;
    unsigned r = v.u + 0x7FFFu + ((v.u >> 16) & 1u);
    return (short)(r >> 16);
}
__device__ __forceinline__ float bf2f(short s) {
    union { unsigned u; float f; } v; v.u = ((unsigned)(unsigned short)s) << 16;
    return v.f;
}
__device__ __forceinline__ float lo_bf(unsigned u) {
    union { unsigned u; float f; } v; v.u = u << 16; return v.f;
}
__device__ __forceinline__ float hi_bf(unsigned u) {
    union { unsigned u; float f; } v; v.u = u & 0xFFFF0000u; return v.f;
}
__device__ __forceinline__ unsigned pack_bf2(float lo, float hi) {
    union { float f; unsigned u; } a, b; a.f = lo; b.f = hi;
    unsigned ul = a.u + 0x7FFFu + ((a.u >> 16) & 1u);
    unsigned uh = b.u + 0x7FFFu + ((b.u >> 16) & 1u);
    return (ul >> 16) | (uh & 0xFFFF0000u);
}

// ---------------------------------------------------------------------------
// Fused misc prep: pad-border zeroing (xpad1/hpa/hpb/xdp) + all weight prep.
__global__ void prep_misc(short* __restrict__ xpad1, short* __restrict__ hpa,
                          short* __restrict__ hpb, short* __restrict__ xdp,
                          const float* __restrict__ ow0, const float* __restrict__ ow1,
                          const float* __restrict__ ow2, const float* __restrict__ ow3,
                          const float* __restrict__ wd,
                          short* __restrict__ wb0, short* __restrict__ wb1,
                          short* __restrict__ wb2, short* __restrict__ wb3,
                          short* __restrict__ wbd) {
    int i = blockIdx.x * 256 + threadIdx.x;
    const int z1 = 4 * 388 * 224, z2 = 4 * 388 * 64;
    if (i < z1 + 2 * z2) {
        short* p; int C;
        if (i < z1) { p = xpad1; C = 224; }
        else if (i < z1 + z2) { p = hpa; C = 64; i -= z1; }
        else { p = hpb; C = 64; i -= z1 + z2; }
        int c = i % C;
        int r = i / C;
        int b = r / 388, pid = r - b * 388;
        int row, col;
        if (pid < 98)       { row = 0;  col = pid; }
        else if (pid < 196) { row = 97; col = pid - 98; }
        else if (pid < 292) { row = pid - 196 + 1; col = 0; }
        else                { row = pid - 292 + 1; col = 97; }
        p[((size_t)b * PHW + row * 98 + col) * C + c] = 0;
        return;
    }
    i -= z1 + 2 * z2;
    const int zr = 4 * 16 * 388 * 8;
    if (i < zr) {
        int c8 = i & 7;
        int r = i >> 3;
        int pid = r % 388;
        int bg = r / 388;
        int row, col;
        if (pid < 98)       { row = 0;  col = pid; }
        else if (pid < 196) { row = 97; col = pid - 98; }
        else if (pid < 292) { row = pid - 196 + 1; col = 0; }
        else                { row = pid - 292 + 1; col = 97; }
        xdp[((size_t)bg * PHW + row * 98 + col) * 8 + c8] = 0;
        return;
    }
    i -= zr;
    const int n0 = 64 * 9 * 224, n1 = 64 * 9 * 64, n3 = 448 * 9 * 64, nd = 64 * 1152;
    if (i < n0) {
        int co = i / (9 * 224); int r = i - co * (9 * 224);
        int tap = r / 224, ci = r - tap * 224;
        wb0[i] = f2bf(ci < 196 ? ow0[(co * 196 + ci) * 9 + tap] : 0.f);
        return;
    }
    i -= n0;
    if (i < n1) {
        int co = i / (9 * 64); int r = i - co * (9 * 64);
        int tap = r / 64, ci = r - tap * 64;
        wb1[i] = f2bf(ow1[(co * 64 + ci) * 9 + tap]);
        return;
    }
    i -= n1;
    if (i < n1) {
        int co = i / (9 * 64); int r = i - co * (9 * 64);
        int tap = r / 64, ci = r - tap * 64;
        wb2[i] = f2bf(ow2[(co * 64 + ci) * 9 + tap]);
        return;
    }
    i -= n1;
    if (i < n3) {
        int co = i / (9 * 64); int r = i - co * (9 * 64);
        int tap = r / 64, ci = r - tap * 64;
        wb3[i] = f2bf(co < 432 ? ow3[(co * 64 + ci) * 9 + tap] : 0.f);
        return;
    }
    i -= n3;
    if (i < nd) {
        int co = i / 1152, kd = i - co * 1152;
        int gt = kd >> 3, c = kd & 7;
        int g = gt / 9, tap = gt - g * 9;
        wbd[i] = f2bf(wd[(co * 128 + g * 8 + c) * 9 + tap]);
    }
}

// ---------------------------------------------------------------------------
// Fused packers. y<7: concat->xpad1. y>=7: x->xdp padded group-planar.
__global__ void pack_all(const float* __restrict__ extra,
                         const float* __restrict__ f1,
                         const float* __restrict__ f2,
                         const float* __restrict__ x,
                         short* __restrict__ xp,
                         short* __restrict__ xdp) {
    __shared__ float t[32][33];
    const int tid = threadIdx.x, tx = tid & 31, ty = tid >> 5;
    const int pt = blockIdx.x, b = blockIdx.z;
    if (blockIdx.y < 7) {
        const int ct = blockIdx.y;
#pragma unroll
        for (int j = 0; j < 4; ++j) {
            int ch = ct * 32 + ty + j * 8;
            int p = pt * 32 + tx;
            float v = 0.f;
            if (ch < 192)      v = extra[(b * 192 + ch) * HW + p];
            else if (ch < 194) v = f1[(b * 2 + ch - 192) * HW + p];
            else if (ch < 196) v = f2[(b * 2 + ch - 194) * HW + p];
            t[ty + j * 8][tx] = v;
        }
        __syncthreads();
#pragma unroll
        for (int j = 0; j < 4; ++j) {
            int pr = ty + j * 8;
            int p = pt * 32 + pr;
            int r = p / 96, c = p - r * 96;
            xp[((size_t)b * PHW + (r + 1) * 98 + (c + 1)) * 224 + ct * 32 + tx] =
                f2bf(t[tx][pr]);
        }
    } else {
        const int ct = blockIdx.y - 7;
#pragma unroll
        for (int j = 0; j < 4; ++j) {
            int ch = ct * 32 + ty + j * 8;
            t[ty + j * 8][tx] = x[((size_t)b * 128 + ch) * HW + pt * 32 + tx];
        }
        __syncthreads();
        if (tid < 128) {
            int oct = tid >> 5, p = tid & 31;
            int g = ct * 4 + oct;
            int pix = pt * 32 + p;
            int r = pix / 96, c = pix - r * 96;
            bh8 v;
#pragma unroll
            for (int cc = 0; cc < 8; ++cc) v[cc] = f2bf(t[oct * 8 + cc][p]);
            *(bh8*)&xdp[(((size_t)b * 16 + g) * PHW + (r + 1) * 98 + (c + 1)) * 8] = v;
        }
    }
}

// ---------------------------------------------------------------------------
// conv1-3 (r8 structure, untouched): block = 4 waves x (16px x 64co),
// weight chunk staged in LDS per 32-cin chunk, B-frags direct global loads.
// ---------------------------------------------------------------------------
template<int CINP, int KCH>
__launch_bounds__(256)
__global__ void conv_mfma(const short* __restrict__ xp,
                          const short* __restrict__ wb,
                          const float* __restrict__ bias,
                          short* __restrict__ o1) {
    __shared__ __attribute__((aligned(16))) short smA[9 * 64 * 32];
    const int tid = threadIdx.x;
    const int lane = tid & 63, wv = tid >> 6;
    const int q = lane >> 4, l15 = lane & 15;
    const int b = blockIdx.y;
    const int pix0 = blockIdx.x * 64 + wv * 16;
    const int soh = pix0 / 96, sow = pix0 - (pix0 / 96) * 96;

    const short* bp = xp + ((size_t)b * PHW + soh * 98 + sow + l15) * CINP + q * 8;

    const int sco = tid >> 2, sqq = tid & 3;
    const short* wsrc = wb + (size_t)sco * (9 * CINP) + sqq * 8;

    f32x4 acc[4];
#pragma unroll
    for (int t = 0; t < 4; ++t) acc[t] = (f32x4){0.f, 0.f, 0.f, 0.f};

    for (int p = 0; p < KCH; ++p) {
        __syncthreads();
        bh8 wtmp[9];
#pragma unroll
        for (int tap = 0; tap < 9; ++tap)
            wtmp[tap] = *(const bh8*)(wsrc + tap * CINP + p * 32);
#pragma unroll
        for (int tap = 0; tap < 9; ++tap)
            *(bh8*)&smA[tap * 2048 + sco * 32 + sqq * 8] = wtmp[tap];
        __syncthreads();
#pragma unroll
        for (int tap = 0; tap < 9; ++tap) {
            const int ky = tap / 3, kx = tap - (tap / 3) * 3;
            bh8 bf = *(const bh8*)(bp + (ky * 98 + kx) * CINP + p * 32);
#pragma unroll
            for (int t = 0; t < 4; ++t) {
                bh8 af = *(const bh8*)&smA[tap * 2048 + (t * 16 + l15) * 32 + q * 8];
                acc[t] = __builtin_amdgcn_mfma_f32_16x16x32_bf16(af, bf, acc[t], 0, 0, 0);
            }
        }
    }

    size_t base = ((size_t)b * PHW + (soh + 1) * 98 + sow + l15 + 1) * 64;
#pragma unroll
    for (int t = 0; t < 4; ++t) {
        bh4 v4;
#pragma unroll
        for (int r = 0; r < 4; ++r) {
            int co = t * 16 + q * 4 + r;
            float v = acc[t][r] + bias[co];
            v = (v >= 0.f) ? v : 0.1f * v;
            v4[r] = f2bf(v);
        }
        *(bh4*)(o1 + base + t * 16 + q * 4) = v4;
    }
}

// ---------------------------------------------------------------------------
// conv4: z=7 co-split. ENTIRE A co-slice staged ONCE in LDS as
// [18 chunk][64 co][32 k] (72 KB, chunk-major = conv1-3's conflict-free
// layout). ONE barrier total; the 18-chunk main loop is barrier-free so
// B-loads for chunk c+1 pipeline under chunk c's MFMAs. Wave = 64 pix x
// 64 co = 16 MFMA/chunk.
// ---------------------------------------------------------------------------
__launch_bounds__(256)
__global__ void conv4_gemm(const short* __restrict__ xp,
                           const short* __restrict__ wb,
                           const float* __restrict__ bias,
                           float* __restrict__ offp,
                           short* __restrict__ maskb,
                           const float* __restrict__ flow1,
                           const float* __restrict__ flow2) {
    __shared__ __attribute__((aligned(16))) short smA[18 * 64 * 32];  // 72 KB
    const int tid = threadIdx.x;
    const int lane = tid & 63, wv = tid >> 6;
    const int q = lane >> 4, l15 = lane & 15;
    const int b = blockIdx.y;
    const int cob = blockIdx.z * 64;
    const int pix0 = blockIdx.x * 256 + wv * 64;

    // one-time A staging: thread (row=tid>>2, slot=tid&3) loads 18 chunks
    {
        const int row = tid >> 2, s = tid & 3;
        const short* asrc = wb + (size_t)(cob + row) * 576 + s * 8;
#pragma unroll
        for (int c = 0; c < 18; ++c) {
            *(bh8*)&smA[c * 2048 + row * 32 + s * 8] = *(const bh8*)(asrc + c * 32);
        }
    }

    const short* bp[4];
#pragma unroll
    for (int s = 0; s < 4; ++s) {
        int pixs = pix0 + s * 16;
        int soh = pixs / 96, sow = pixs - (pixs / 96) * 96;
        bp[s] = xp + ((size_t)b * PHW + soh * 98 + sow + l15) * 64 + q * 8;
    }

    f32x4 acc[4][4];
#pragma unroll
    for (int cf = 0; cf < 4; ++cf)
#pragma unroll
        for (int s = 0; s < 4; ++s) acc[cf][s] = (f32x4){0.f, 0.f, 0.f, 0.f};

    __syncthreads();

#pragma unroll 2
    for (int ch = 0; ch < 18; ++ch) {
        const int tap = ch >> 1, kc = ch & 1;
        const int ky = tap / 3, kx = tap - (tap / 3) * 3;
        bh8 bf[4], af[4];
#pragma unroll
        for (int s = 0; s < 4; ++s)
            bf[s] = *(const bh8*)(bp[s] + (ky * 98 + kx) * 64 + kc * 32);
#pragma unroll
        for (int cf = 0; cf < 4; ++cf)
            af[cf] = *(const bh8*)&smA[ch * 2048 + (cf * 16 + l15) * 32 + q * 8];
#pragma unroll
        for (int cf = 0; cf < 4; ++cf)
#pragma unroll
            for (int s = 0; s < 4; ++s)
                acc[cf][s] = __builtin_amdgcn_mfma_f32_16x16x32_bf16(
                    af[cf], bf[s], acc[cf][s], 0, 0, 0);
    }

#pragma unroll
    for (int s = 0; s < 4; ++s) {
        int pix = pix0 + s * 16 + l15;
#pragma unroll
        for (int cf = 0; cf < 4; ++cf) {
            int cb0 = cob + cf * 16 + q * 4;
            if (cb0 < 288) {
                const float* fl = (cb0 < 144) ? flow1 : flow2;
                float fe = fl[(b * 2 + 1) * HW + pix];
                float fo = fl[(b * 2) * HW + pix];
                float t0 = 10.f * tanhf(acc[cf][s][0] + bias[cb0 + 0]) + fe;
                float t1 = 10.f * tanhf(acc[cf][s][1] + bias[cb0 + 1]) + fo;
                float t2 = 10.f * tanhf(acc[cf][s][2] + bias[cb0 + 2]) + fe;
                float t3 = 10.f * tanhf(acc[cf][s][3] + bias[cb0 + 3]) + fo;
                size_t p0 = ((size_t)b * 144 + (cb0 >> 1)) * HW + pix;
                *(f32x2*)&offp[p0 * 2] = (f32x2){t0, t1};
                *(f32x2*)&offp[(p0 + HW) * 2] = (f32x2){t2, t3};
            } else {
#pragma unroll
                for (int r = 0; r < 4; ++r) {
                    int chn = cb0 + r;
                    if (chn < 432) {
                        float v = acc[cf][s][r] + bias[chn];
                        maskb[((size_t)b * 144 + (chn - 288)) * HW + pix] =
                            f2bf(1.f / (1.f + expf(-v)));
                    }
                }
            }
        }
    }
}

// ---------------------------------------------------------------------------
// Deform (r8 version): padded zero-ring xdp, packed bf16 math,
// precomputed pointers, XCD-swizzled blocks.
// ---------------------------------------------------------------------------
__launch_bounds__(256)
__global__ void deform_mfma(const short* __restrict__ xdp,
                            const float* __restrict__ offp,
                            const short* __restrict__ maskb,
                            const short* __restrict__ wbd,
                            const float* __restrict__ bias,
                            float* __restrict__ out) {
    __shared__ float red[4][1024];
    const int tid = threadIdx.x;
    const int lane = tid & 63, wv = tid >> 6;
    const int q = lane >> 4, l15 = lane & 15;
    const int blk = blockIdx.x;
    const int xs = blk & 7, idx = blk >> 3;
    const int b = xs >> 1;
    const int pix0 = ((xs & 1) * 288 + idx) * 16;
    const int pix = pix0 + l15;
    const int h = pix / 96, w = pix - (pix / 96) * 96;

    const float* opp = offp + ((size_t)b * 144 * HW + pix) * 2;
    const short* mp = maskb + (size_t)b * 144 * HW + pix;
    const short* xb = xdp + (size_t)b * 16 * PHW * 8;
    const short* ap = wbd + (size_t)l15 * 1152 + wv * 288 + q * 8;

    f32x2 dxy[9];
    float mk[9];
#pragma unroll
    for (int i = 0; i < 9; ++i) {
        const int gt = wv * 36 + i * 4 + q;
        dxy[i] = *(const f32x2*)(opp + (size_t)gt * HW * 2);
        mk[i] = bf2f(mp[(size_t)gt * HW]);
    }

    const short* cp[9];
    f32x4 ww[9];
#pragma unroll
    for (int i = 0; i < 9; ++i) {
        const int gt = wv * 36 + i * 4 + q;
        const int g = gt / 9, tap = gt - (gt / 9) * 9;
        float py = dxy[i][0] + (float)(tap / 3) + (float)h - 1.f;
        float px = dxy[i][1] + (float)(tap - (tap / 3) * 3) + (float)w - 1.f;
        py = fminf(fmaxf(py, -1.f), 96.f);
        px = fminf(fmaxf(px, -1.f), 96.f);
        float y0f = floorf(py), x0f = floorf(px);
        float wy1 = py - y0f, wx1 = px - x0f;
        float wy0 = 1.f - wy1, wx0 = 1.f - wx1;
        int yp = (int)y0f + 1, xp = (int)x0f + 1;
        cp[i] = xb + ((size_t)g * PHW + yp * 98 + xp) * 8;
        float m = mk[i];
        ww[i] = (f32x4){wy0 * wx0 * m, wy0 * wx1 * m, wy1 * wx0 * m, wy1 * wx1 * m};
    }

    f32x4 acc[4];
#pragma unroll
    for (int t = 0; t < 4; ++t) acc[t] = (f32x4){0.f, 0.f, 0.f, 0.f};

#pragma unroll
    for (int i = 0; i < 9; ++i) {
        bh8i c00, c01, c10, c11;
        c00.v = *(const bh8*)(cp[i]);
        c01.v = *(const bh8*)(cp[i] + 8);
        c10.v = *(const bh8*)(cp[i] + 98 * 8);
        c11.v = *(const bh8*)(cp[i] + 99 * 8);
        const float w00 = ww[i][0], w01 = ww[i][1], w10 = ww[i][2], w11 = ww[i][3];
        bh8i bf;
#pragma unroll
        for (int k = 0; k < 4; ++k) {
            unsigned u00 = (unsigned)c00.i[k], u01 = (unsigned)c01.i[k];
            unsigned u10 = (unsigned)c10.i[k], u11 = (unsigned)c11.i[k];
            float lo = w00 * lo_bf(u00) + w01 * lo_bf(u01)
                     + w10 * lo_bf(u10) + w11 * lo_bf(u11);
            float hi = w00 * hi_bf(u00) + w01 * hi_bf(u01)
                     + w10 * hi_bf(u10) + w11 * hi_bf(u11);
            bf.i[k] = (int)pack_bf2(lo, hi);
        }
#pragma unroll
        for (int t = 0; t < 4; ++t) {
            bh8 af = *(const bh8*)(ap + (size_t)t * 16 * 1152 + i * 32);
            acc[t] = __builtin_amdgcn_mfma_f32_16x16x32_bf16(af, bf.v, acc[t], 0, 0, 0);
        }
    }

#pragma unroll
    for (int t = 0; t < 4; ++t)
#pragma unroll
        for (int r = 0; r < 4; ++r)
            red[wv][(t * 16 + q * 4 + r) * 16 + l15] = acc[t][r];
    __syncthreads();
    for (int e = tid; e < 1024; e += 256) {
        int co = e >> 4, pl = e & 15;
        float v = red[0][e] + red[1][e] + red[2][e] + red[3][e] + bias[co];
        out[((size_t)b * 64 + co) * HW + pix0 + pl] = v;
    }
}

// ---------------------------------------------------------------------------
extern "C" void kernel_launch(void* const* d_in, const int* in_sizes, int n_in,
                              void* d_out, int out_size, void* d_ws, size_t ws_size,
                              hipStream_t stream) {
    const float* x      = (const float*)d_in[0];
    const float* extra  = (const float*)d_in[1];
    const float* flow1  = (const float*)d_in[2];
    const float* flow2  = (const float*)d_in[3];
    const float* weight = (const float*)d_in[4];
    const float* bias   = (const float*)d_in[5];
    const float* ow0    = (const float*)d_in[6];
    const float* ob0    = (const float*)d_in[7];
    const float* ow1    = (const float*)d_in[8];
    const float* ob1    = (const float*)d_in[9];
    const float* ow2    = (const float*)d_in[10];
    const float* ob2    = (const float*)d_in[11];
    const float* ow3    = (const float*)d_in[12];
    const float* ob3    = (const float*)d_in[13];
    float* out = (float*)d_out;

    char* wsb = (char*)d_ws;
    short* xpad1 = (short*)wsb;   wsb += (size_t)4 * PHW * 224 * 2;
    short* hpa   = (short*)wsb;   wsb += (size_t)4 * PHW * 64 * 2;
    short* hpb   = (short*)wsb;   wsb += (size_t)4 * PHW * 64 * 2;
    float* offpair = (float*)wsb; wsb += (size_t)4 * 144 * HW * 2 * 4;
    short* maskbuf = (short*)wsb; wsb += (size_t)4 * 144 * HW * 2;
    short* xdp     = (short*)wsb; wsb += (size_t)4 * 16 * PHW * 8 * 2 + 32;
    short* wb0     = (short*)wsb; wsb += 64 * 9 * 224 * 2;
    short* wb1     = (short*)wsb; wsb += 64 * 9 * 64 * 2;
    short* wb2     = (short*)wsb; wsb += 64 * 9 * 64 * 2;
    short* wb3     = (short*)wsb; wsb += 448 * 9 * 64 * 2;
    short* wbd     = (short*)wsb;

    const int prep_total = 546304 + 198656 + 534528;
    prep_misc<<<dim3((prep_total + 255) / 256), 256, 0, stream>>>(
        xpad1, hpa, hpb, xdp, ow0, ow1, ow2, ow3, weight,
        wb0, wb1, wb2, wb3, wbd);
    pack_all<<<dim3(288, 11, 4), 256, 0, stream>>>(extra, flow1, flow2, x, xpad1, xdp);

    conv_mfma<224, 7><<<dim3(144, 4), 256, 0, stream>>>(xpad1, wb0, ob0, hpa);
    conv_mfma<64, 2><<<dim3(144, 4), 256, 0, stream>>>(hpa, wb1, ob1, hpb);
    conv_mfma<64, 2><<<dim3(144, 4), 256, 0, stream>>>(hpb, wb2, ob2, hpa);
    conv4_gemm<<<dim3(36, 4, 7), 256, 0, stream>>>(hpa, wb3, ob3, offpair,
                                                   maskbuf, flow1, flow2);
    deform_mfma<<<dim3(2304), 256, 0, stream>>>(xdp, offpair, maskbuf, wbd, bias, out);
}

// Round 12
// 314.465 us; speedup vs baseline: 1.0328x; 1.0328x over previous
//
#include <hip/hip_runtime.h>
#include <math.h>

#define HW 9216
#define Hh 96
#define Ww 96
#define PHW 9604   // 98*98 padded

typedef __attribute__((ext_vector_type(8))) short bh8;
typedef __attribute__((ext_vector_type(4))) short bh4;
typedef __attribute__((ext_vector_type(4))) float f32x4;
typedef __attribute__((ext_vector_type(2))) float f32x2;
typedef __attribute__((ext_vector_type(4))) int i32x4;
union bh8i { bh8 v; i32x4 i; };

__device__ __forceinline__ short f2bf(float f) {
    union { float f; unsigned u; } v; v.f = f;
    unsigned r = v.u + 0x7FFFu + ((v.u >> 16) & 1u);
    return (short)(r >> 16);
}
__device__ __forceinline__ float bf2f(short s) {
    union { unsigned u; float f; } v; v.u = ((unsigned)(unsigned short)s) << 16;
    return v.f;
}
__device__ __forceinline__ float lo_bf(unsigned u) {
    union { unsigned u; float f; } v; v.u = u << 16; return v.f;
}
__device__ __forceinline__ float hi_bf(unsigned u) {
    union { unsigned u; float f; } v; v.u = u & 0xFFFF0000u; return v.f;
}
__device__ __forceinline__ unsigned pack_bf2(float lo, float hi) {
    union { float f; unsigned u; } a, b; a.f = lo; b.f = hi;
    unsigned ul = a.u + 0x7FFFu + ((a.u >> 16) & 1u);
    unsigned uh = b.u + 0x7FFFu + ((b.u >> 16) & 1u);
    return (ul >> 16) | (uh & 0xFFFF0000u);
}

// async global->LDS, 16 B per lane; LDS dest = wave-uniform base + lane*16.
__device__ __forceinline__ void async_lds16(const short* g, short* l) {
    __builtin_amdgcn_global_load_lds(
        (const __attribute__((address_space(1))) unsigned int*)g,
        (__attribute__((address_space(3))) unsigned int*)l,
        16, 0, 0);
}

// ---------------------------------------------------------------------------
// Fused misc prep: pad-border zeroing (xpad1/hpa/hpb/xdp) + all weight prep.
__global__ void prep_misc(short* __restrict__ xpad1, short* __restrict__ hpa,
                          short* __restrict__ hpb, short* __restrict__ xdp,
                          const float* __restrict__ ow0, const float* __restrict__ ow1,
                          const float* __restrict__ ow2, const float* __restrict__ ow3,
                          const float* __restrict__ wd,
                          short* __restrict__ wb0, short* __restrict__ wb1,
                          short* __restrict__ wb2, short* __restrict__ wb3,
                          short* __restrict__ wbd) {
    int i = blockIdx.x * 256 + threadIdx.x;
    const int z1 = 4 * 388 * 224, z2 = 4 * 388 * 64;
    if (i < z1 + 2 * z2) {
        short* p; int C;
        if (i < z1) { p = xpad1; C = 224; }
        else if (i < z1 + z2) { p = hpa; C = 64; i -= z1; }
        else { p = hpb; C = 64; i -= z1 + z2; }
        int c = i % C;
        int r = i / C;
        int b = r / 388, pid = r - b * 388;
        int row, col;
        if (pid < 98)       { row = 0;  col = pid; }
        else if (pid < 196) { row = 97; col = pid - 98; }
        else if (pid < 292) { row = pid - 196 + 1; col = 0; }
        else                { row = pid - 292 + 1; col = 97; }
        p[((size_t)b * PHW + row * 98 + col) * C + c] = 0;
        return;
    }
    i -= z1 + 2 * z2;
    const int zr = 4 * 16 * 388 * 8;
    if (i < zr) {
        int c8 = i & 7;
        int r = i >> 3;
        int pid = r % 388;
        int bg = r / 388;
        int row, col;
        if (pid < 98)       { row = 0;  col = pid; }
        else if (pid < 196) { row = 97; col = pid - 98; }
        else if (pid < 292) { row = pid - 196 + 1; col = 0; }
        else                { row = pid - 292 + 1; col = 97; }
        xdp[((size_t)bg * PHW + row * 98 + col) * 8 + c8] = 0;
        return;
    }
    i -= zr;
    const int n0 = 64 * 9 * 224, n1 = 64 * 9 * 64, n3 = 448 * 9 * 64, nd = 64 * 1152;
    if (i < n0) {
        int co = i / (9 * 224); int r = i - co * (9 * 224);
        int tap = r / 224, ci = r - tap * 224;
        wb0[i] = f2bf(ci < 196 ? ow0[(co * 196 + ci) * 9 + tap] : 0.f);
        return;
    }
    i -= n0;
    if (i < n1) {
        int co = i / (9 * 64); int r = i - co * (9 * 64);
        int tap = r / 64, ci = r - tap * 64;
        wb1[i] = f2bf(ow1[(co * 64 + ci) * 9 + tap]);
        return;
    }
    i -= n1;
    if (i < n1) {
        int co = i / (9 * 64); int r = i - co * (9 * 64);
        int tap = r / 64, ci = r - tap * 64;
        wb2[i] = f2bf(ow2[(co * 64 + ci) * 9 + tap]);
        return;
    }
    i -= n1;
    if (i < n3) {
        int co = i / (9 * 64); int r = i - co * (9 * 64);
        int tap = r / 64, ci = r - tap * 64;
        wb3[i] = f2bf(co < 432 ? ow3[(co * 64 + ci) * 9 + tap] : 0.f);
        return;
    }
    i -= n3;
    if (i < nd) {
        int co = i / 1152, kd = i - co * 1152;
        int gt = kd >> 3, c = kd & 7;
        int g = gt / 9, tap = gt - g * 9;
        wbd[i] = f2bf(wd[(co * 128 + g * 8 + c) * 9 + tap]);
    }
}

// ---------------------------------------------------------------------------
// Fused packers. y<7: concat->xpad1. y>=7: x->xdp padded group-planar.
__global__ void pack_all(const float* __restrict__ extra,
                         const float* __restrict__ f1,
                         const float* __restrict__ f2,
                         const float* __restrict__ x,
                         short* __restrict__ xp,
                         short* __restrict__ xdp) {
    __shared__ float t[32][33];
    const int tid = threadIdx.x, tx = tid & 31, ty = tid >> 5;
    const int pt = blockIdx.x, b = blockIdx.z;
    if (blockIdx.y < 7) {
        const int ct = blockIdx.y;
#pragma unroll
        for (int j = 0; j < 4; ++j) {
            int ch = ct * 32 + ty + j * 8;
            int p = pt * 32 + tx;
            float v = 0.f;
            if (ch < 192)      v = extra[(b * 192 + ch) * HW + p];
            else if (ch < 194) v = f1[(b * 2 + ch - 192) * HW + p];
            else if (ch < 196) v = f2[(b * 2 + ch - 194) * HW + p];
            t[ty + j * 8][tx] = v;
        }
        __syncthreads();
#pragma unroll
        for (int j = 0; j < 4; ++j) {
            int pr = ty + j * 8;
            int p = pt * 32 + pr;
            int r = p / 96, c = p - r * 96;
            xp[((size_t)b * PHW + (r + 1) * 98 + (c + 1)) * 224 + ct * 32 + tx] =
                f2bf(t[tx][pr]);
        }
    } else {
        const int ct = blockIdx.y - 7;
#pragma unroll
        for (int j = 0; j < 4; ++j) {
            int ch = ct * 32 + ty + j * 8;
            t[ty + j * 8][tx] = x[((size_t)b * 128 + ch) * HW + pt * 32 + tx];
        }
        __syncthreads();
        if (tid < 128) {
            int oct = tid >> 5, p = tid & 31;
            int g = ct * 4 + oct;
            int pix = pt * 32 + p;
            int r = pix / 96, c = pix - r * 96;
            bh8 v;
#pragma unroll
            for (int cc = 0; cc < 8; ++cc) v[cc] = f2bf(t[oct * 8 + cc][p]);
            *(bh8*)&xdp[(((size_t)b * 16 + g) * PHW + (r + 1) * 98 + (c + 1)) * 8] = v;
        }
    }
}

// ---------------------------------------------------------------------------
// conv1-3 (r8 structure, untouched): block = 4 waves x (16px x 64co),
// weight chunk staged in LDS per 32-cin chunk, B-frags direct global loads.
// ---------------------------------------------------------------------------
template<int CINP, int KCH>
__launch_bounds__(256)
__global__ void conv_mfma(const short* __restrict__ xp,
                          const short* __restrict__ wb,
                          const float* __restrict__ bias,
                          short* __restrict__ o1) {
    __shared__ __attribute__((aligned(16))) short smA[9 * 64 * 32];
    const int tid = threadIdx.x;
    const int lane = tid & 63, wv = tid >> 6;
    const int q = lane >> 4, l15 = lane & 15;
    const int b = blockIdx.y;
    const int pix0 = blockIdx.x * 64 + wv * 16;
    const int soh = pix0 / 96, sow = pix0 - (pix0 / 96) * 96;

    const short* bp = xp + ((size_t)b * PHW + soh * 98 + sow + l15) * CINP + q * 8;

    const int sco = tid >> 2, sqq = tid & 3;
    const short* wsrc = wb + (size_t)sco * (9 * CINP) + sqq * 8;

    f32x4 acc[4];
#pragma unroll
    for (int t = 0; t < 4; ++t) acc[t] = (f32x4){0.f, 0.f, 0.f, 0.f};

    for (int p = 0; p < KCH; ++p) {
        __syncthreads();
        bh8 wtmp[9];
#pragma unroll
        for (int tap = 0; tap < 9; ++tap)
            wtmp[tap] = *(const bh8*)(wsrc + tap * CINP + p * 32);
#pragma unroll
        for (int tap = 0; tap < 9; ++tap)
            *(bh8*)&smA[tap * 2048 + sco * 32 + sqq * 8] = wtmp[tap];
        __syncthreads();
#pragma unroll
        for (int tap = 0; tap < 9; ++tap) {
            const int ky = tap / 3, kx = tap - (tap / 3) * 3;
            bh8 bf = *(const bh8*)(bp + (ky * 98 + kx) * CINP + p * 32);
#pragma unroll
            for (int t = 0; t < 4; ++t) {
                bh8 af = *(const bh8*)&smA[tap * 2048 + (t * 16 + l15) * 32 + q * 8];
                acc[t] = __builtin_amdgcn_mfma_f32_16x16x32_bf16(af, bf, acc[t], 0, 0, 0);
            }
        }
    }

    size_t base = ((size_t)b * PHW + (soh + 1) * 98 + sow + l15 + 1) * 64;
#pragma unroll
    for (int t = 0; t < 4; ++t) {
        bh4 v4;
#pragma unroll
        for (int r = 0; r < 4; ++r) {
            int co = t * 16 + q * 4 + r;
            float v = acc[t][r] + bias[co];
            v = (v >= 0.f) ? v : 0.1f * v;
            v4[r] = f2bf(v);
        }
        *(bh4*)(o1 + base + t * 16 + q * 4) = v4;
    }
}

// ---------------------------------------------------------------------------
// conv4: z=7 co-split, block = 64 co x 192 px (4 waves x 48 px).
// 3 phases; each phase async-stages A for 3 taps (6 k-chunks, 24 KB) via
// global_load_lds width-16 (wave wv stages co rows wv*16..wv*16+15 of every
// chunk: LDS dest = chunk base + wv*1024B + lane*16B, matching the HW
// wave-uniform+lane*16 rule), then runs 6 chunks BARRIER-FREE so each wave's
// 18 B-global-loads pipeline under MFMA. 6 barriers total (vs 36 in r8).
// ---------------------------------------------------------------------------
__launch_bounds__(256, 2)
__global__ void conv4_gemm(const short* __restrict__ xp,
                           const short* __restrict__ wb,
                           const float* __restrict__ bias,
                           float* __restrict__ offp,
                           short* __restrict__ maskb,
                           const float* __restrict__ flow1,
                           const float* __restrict__ flow2) {
    __shared__ __attribute__((aligned(16))) short smA[6 * 64 * 32];   // 24 KB
    const int tid = threadIdx.x;
    const int lane = tid & 63, wv = tid >> 6;
    const int q = lane >> 4, l15 = lane & 15;
    const int b = blockIdx.y;
    const int cob = blockIdx.z * 64;
    const int pixw = blockIdx.x * 192 + wv * 48;

    const short* bp[3];
#pragma unroll
    for (int s = 0; s < 3; ++s) {
        int pixs = pixw + s * 16;
        int soh = pixs / 96, sow = pixs - (pixs / 96) * 96;
        bp[s] = xp + ((size_t)b * PHW + soh * 98 + sow + l15) * 64 + q * 8;
    }

    // staging source: lane covers co row (cob + wv*16 + (lane>>2)), slot lane&3
    const short* asrc = wb + (size_t)(cob + wv * 16 + (lane >> 2)) * 576 + (lane & 3) * 8;
    short* sdst = &smA[wv * 512];   // + chunk*2048

    f32x4 acc[4][3];
#pragma unroll
    for (int cf = 0; cf < 4; ++cf)
#pragma unroll
        for (int s = 0; s < 3; ++s) acc[cf][s] = (f32x4){0.f, 0.f, 0.f, 0.f};

#pragma unroll
    for (int ph = 0; ph < 3; ++ph) {
        __syncthreads();          // all waves done reading previous phase
#pragma unroll
        for (int c6 = 0; c6 < 6; ++c6) {
            const int tap = ph * 3 + (c6 >> 1), kc = c6 & 1;
            async_lds16(asrc + tap * 64 + kc * 32, sdst + c6 * 2048);
        }
        __syncthreads();          // drain async staging (vmcnt)
#pragma unroll
        for (int c6 = 0; c6 < 6; ++c6) {
            const int tap = ph * 3 + (c6 >> 1), kc = c6 & 1;
            const int ky = tap / 3, kx = tap - (tap / 3) * 3;
            bh8 bf[3], af[4];
#pragma unroll
            for (int s = 0; s < 3; ++s)
                bf[s] = *(const bh8*)(bp[s] + (ky * 98 + kx) * 64 + kc * 32);
#pragma unroll
            for (int cf = 0; cf < 4; ++cf)
                af[cf] = *(const bh8*)&smA[c6 * 2048 + (cf * 16 + l15) * 32 + q * 8];
#pragma unroll
            for (int cf = 0; cf < 4; ++cf)
#pragma unroll
                for (int s = 0; s < 3; ++s)
                    acc[cf][s] = __builtin_amdgcn_mfma_f32_16x16x32_bf16(
                        af[cf], bf[s], acc[cf][s], 0, 0, 0);
        }
    }

#pragma unroll
    for (int s = 0; s < 3; ++s) {
        int pix = pixw + s * 16 + l15;
#pragma unroll
        for (int cf = 0; cf < 4; ++cf) {
            int cb0 = cob + cf * 16 + q * 4;
            if (cb0 < 288) {
                const float* fl = (cb0 < 144) ? flow1 : flow2;
                float fe = fl[(b * 2 + 1) * HW + pix];
                float fo = fl[(b * 2) * HW + pix];
                float t0 = 10.f * tanhf(acc[cf][s][0] + bias[cb0 + 0]) + fe;
                float t1 = 10.f * tanhf(acc[cf][s][1] + bias[cb0 + 1]) + fo;
                float t2 = 10.f * tanhf(acc[cf][s][2] + bias[cb0 + 2]) + fe;
                float t3 = 10.f * tanhf(acc[cf][s][3] + bias[cb0 + 3]) + fo;
                size_t p0 = ((size_t)b * 144 + (cb0 >> 1)) * HW + pix;
                *(f32x2*)&offp[p0 * 2] = (f32x2){t0, t1};
                *(f32x2*)&offp[(p0 + HW) * 2] = (f32x2){t2, t3};
            } else {
#pragma unroll
                for (int r = 0; r < 4; ++r) {
                    int chn = cb0 + r;
                    if (chn < 432) {
                        float v = acc[cf][s][r] + bias[chn];
                        maskb[((size_t)b * 144 + (chn - 288)) * HW + pix] =
                            f2bf(1.f / (1.f + expf(-v)));
                    }
                }
            }
        }
    }
}

// ---------------------------------------------------------------------------
// Deform (r8 structure): padded zero-ring xdp, packed bf16 math, precomputed
// pointers, XCD-swizzled blocks. launch_bounds (256,2) releases the VGPR cap
// (was 64) so the scheduler can hoist the 36 corner gathers deeper.
// ---------------------------------------------------------------------------
__launch_bounds__(256, 2)
__global__ void deform_mfma(const short* __restrict__ xdp,
                            const float* __restrict__ offp,
                            const short* __restrict__ maskb,
                            const short* __restrict__ wbd,
                            const float* __restrict__ bias,
                            float* __restrict__ out) {
    __shared__ float red[4][1024];
    const int tid = threadIdx.x;
    const int lane = tid & 63, wv = tid >> 6;
    const int q = lane >> 4, l15 = lane & 15;
    const int blk = blockIdx.x;
    const int xs = blk & 7, idx = blk >> 3;
    const int b = xs >> 1;
    const int pix0 = ((xs & 1) * 288 + idx) * 16;
    const int pix = pix0 + l15;
    const int h = pix / 96, w = pix - (pix / 96) * 96;

    const float* opp = offp + ((size_t)b * 144 * HW + pix) * 2;
    const short* mp = maskb + (size_t)b * 144 * HW + pix;
    const short* xb = xdp + (size_t)b * 16 * PHW * 8;
    const short* ap = wbd + (size_t)l15 * 1152 + wv * 288 + q * 8;

    f32x2 dxy[9];
    float mk[9];
#pragma unroll
    for (int i = 0; i < 9; ++i) {
        const int gt = wv * 36 + i * 4 + q;
        dxy[i] = *(const f32x2*)(opp + (size_t)gt * HW * 2);
        mk[i] = bf2f(mp[(size_t)gt * HW]);
    }

    const short* cp[9];
    f32x4 ww[9];
#pragma unroll
    for (int i = 0; i < 9; ++i) {
        const int gt = wv * 36 + i * 4 + q;
        const int g = gt / 9, tap = gt - (gt / 9) * 9;
        float py = dxy[i][0] + (float)(tap / 3) + (float)h - 1.f;
        float px = dxy[i][1] + (float)(tap - (tap / 3) * 3) + (float)w - 1.f;
        py = fminf(fmaxf(py, -1.f), 96.f);
        px = fminf(fmaxf(px, -1.f), 96.f);
        float y0f = floorf(py), x0f = floorf(px);
        float wy1 = py - y0f, wx1 = px - x0f;
        float wy0 = 1.f - wy1, wx0 = 1.f - wx1;
        int yp = (int)y0f + 1, xp = (int)x0f + 1;
        cp[i] = xb + ((size_t)g * PHW + yp * 98 + xp) * 8;
        float m = mk[i];
        ww[i] = (f32x4){wy0 * wx0 * m, wy0 * wx1 * m, wy1 * wx0 * m, wy1 * wx1 * m};
    }

    f32x4 acc[4];
#pragma unroll
    for (int t = 0; t < 4; ++t) acc[t] = (f32x4){0.f, 0.f, 0.f, 0.f};

#pragma unroll
    for (int i = 0; i < 9; ++i) {
        bh8i c00, c01, c10, c11;
        c00.v = *(const bh8*)(cp[i]);
        c01.v = *(const bh8*)(cp[i] + 8);
        c10.v = *(const bh8*)(cp[i] + 98 * 8);
        c11.v = *(const bh8*)(cp[i] + 99 * 8);
        const float w00 = ww[i][0], w01 = ww[i][1], w10 = ww[i][2], w11 = ww[i][3];
        bh8i bf;
#pragma unroll
        for (int k = 0; k < 4; ++k) {
            unsigned u00 = (unsigned)c00.i[k], u01 = (unsigned)c01.i[k];
            unsigned u10 = (unsigned)c10.i[k], u11 = (unsigned)c11.i[k];
            float lo = w00 * lo_bf(u00) + w01 * lo_bf(u01)
                     + w10 * lo_bf(u10) + w11 * lo_bf(u11);
            float hi = w00 * hi_bf(u00) + w01 * hi_bf(u01)
                     + w10 * hi_bf(u10) + w11 * hi_bf(u11);
            bf.i[k] = (int)pack_bf2(lo, hi);
        }
#pragma unroll
        for (int t = 0; t < 4; ++t) {
            bh8 af = *(const bh8*)(ap + (size_t)t * 16 * 1152 + i * 32);
            acc[t] = __builtin_amdgcn_mfma_f32_16x16x32_bf16(af, bf.v, acc[t], 0, 0, 0);
        }
    }

#pragma unroll
    for (int t = 0; t < 4; ++t)
#pragma unroll
        for (int r = 0; r < 4; ++r)
            red[wv][(t * 16 + q * 4 + r) * 16 + l15] = acc[t][r];
    __syncthreads();
    for (int e = tid; e < 1024; e += 256) {
        int co = e >> 4, pl = e & 15;
        float v = red[0][e] + red[1][e] + red[2][e] + red[3][e] + bias[co];
        out[((size_t)b * 64 + co) * HW + pix0 + pl] = v;
    }
}

// ---------------------------------------------------------------------------
extern "C" void kernel_launch(void* const* d_in, const int* in_sizes, int n_in,
                              void* d_out, int out_size, void* d_ws, size_t ws_size,
                              hipStream_t stream) {
    const float* x      = (const float*)d_in[0];
    const float* extra  = (const float*)d_in[1];
    const float* flow1  = (const float*)d_in[2];
    const float* flow2  = (const float*)d_in[3];
    const float* weight = (const float*)d_in[4];
    const float* bias   = (const float*)d_in[5];
    const float* ow0    = (const float*)d_in[6];
    const float* ob0    = (const float*)d_in[7];
    const float* ow1    = (const float*)d_in[8];
    const float* ob1    = (const float*)d_in[9];
    const float* ow2    = (const float*)d_in[10];
    const float* ob2    = (const float*)d_in[11];
    const float* ow3    = (const float*)d_in[12];
    const float* ob3    = (const float*)d_in[13];
    float* out = (float*)d_out;

    char* wsb = (char*)d_ws;
    short* xpad1 = (short*)wsb;   wsb += (size_t)4 * PHW * 224 * 2;
    short* hpa   = (short*)wsb;   wsb += (size_t)4 * PHW * 64 * 2;
    short* hpb   = (short*)wsb;   wsb += (size_t)4 * PHW * 64 * 2;
    float* offpair = (float*)wsb; wsb += (size_t)4 * 144 * HW * 2 * 4;
    short* maskbuf = (short*)wsb; wsb += (size_t)4 * 144 * HW * 2;
    short* xdp     = (short*)wsb; wsb += (size_t)4 * 16 * PHW * 8 * 2 + 32;
    short* wb0     = (short*)wsb; wsb += 64 * 9 * 224 * 2;
    short* wb1     = (short*)wsb; wsb += 64 * 9 * 64 * 2;
    short* wb2     = (short*)wsb; wsb += 64 * 9 * 64 * 2;
    short* wb3     = (short*)wsb; wsb += 448 * 9 * 64 * 2;
    short* wbd     = (short*)wsb;

    const int prep_total = 546304 + 198656 + 534528;
    prep_misc<<<dim3((prep_total + 255) / 256), 256, 0, stream>>>(
        xpad1, hpa, hpb, xdp, ow0, ow1, ow2, ow3, weight,
        wb0, wb1, wb2, wb3, wbd);
    pack_all<<<dim3(288, 11, 4), 256, 0, stream>>>(extra, flow1, flow2, x, xpad1, xdp);

    conv_mfma<224, 7><<<dim3(144, 4), 256, 0, stream>>>(xpad1, wb0, ob0, hpa);
    conv_mfma<64, 2><<<dim3(144, 4), 256, 0, stream>>>(hpa, wb1, ob1, hpb);
    conv_mfma<64, 2><<<dim3(144, 4), 256, 0, stream>>>(hpb, wb2, ob2, hpa);
    conv4_gemm<<<dim3(48, 4, 7), 256, 0, stream>>>(hpa, wb3, ob3, offpair,
                                                   maskbuf, flow1, flow2);
    deform_mfma<<<dim3(2304), 256, 0, stream>>>(xdp, offpair, maskbuf, wbd, bias, out);
}

// Round 13
// 305.760 us; speedup vs baseline: 1.0622x; 1.0285x over previous
//
#include <hip/hip_runtime.h>
#include <math.h>

#define HW 9216
#define Hh 96
#define Ww 96
#define PHW 9604   // 98*98 padded

typedef __attribute__((ext_vector_type(8))) short bh8;
typedef __attribute__((ext_vector_type(4))) short bh4;
typedef __attribute__((ext_vector_type(4))) float f32x4;
typedef __attribute__((ext_vector_type(2))) float f32x2;
typedef __attribute__((ext_vector_type(4))) int i32x4;
typedef __attribute__((ext_vector_type(2))) _Float16 h16x2;
union bh8i { bh8 v; i32x4 i; };

__device__ __forceinline__ short f2bf(float f) {
    union { float f; unsigned u; } v; v.f = f;
    unsigned r = v.u + 0x7FFFu + ((v.u >> 16) & 1u);
    return (short)(r >> 16);
}
__device__ __forceinline__ float bf2f(short s) {
    union { unsigned u; float f; } v; v.u = ((unsigned)(unsigned short)s) << 16;
    return v.f;
}
__device__ __forceinline__ float lo_bf(unsigned u) {
    union { unsigned u; float f; } v; v.u = u << 16; return v.f;
}
__device__ __forceinline__ float hi_bf(unsigned u) {
    union { unsigned u; float f; } v; v.u = u & 0xFFFF0000u; return v.f;
}
__device__ __forceinline__ unsigned pack_bf2(float lo, float hi) {
    union { float f; unsigned u; } a, b; a.f = lo; b.f = hi;
    unsigned ul = a.u + 0x7FFFu + ((a.u >> 16) & 1u);
    unsigned uh = b.u + 0x7FFFu + ((b.u >> 16) & 1u);
    return (ul >> 16) | (uh & 0xFFFF0000u);
}

// async global->LDS, 16 B per lane; LDS dest = wave-uniform base + lane*16.
__device__ __forceinline__ void async_lds16(const short* g, short* l) {
    __builtin_amdgcn_global_load_lds(
        (const __attribute__((address_space(1))) unsigned int*)g,
        (__attribute__((address_space(3))) unsigned int*)l,
        16, 0, 0);
}

// ---------------------------------------------------------------------------
// Fused misc prep: pad-border zeroing (xpad1/hpa/hpb/xdp) + all weight prep.
__global__ void prep_misc(short* __restrict__ xpad1, short* __restrict__ hpa,
                          short* __restrict__ hpb, short* __restrict__ xdp,
                          const float* __restrict__ ow0, const float* __restrict__ ow1,
                          const float* __restrict__ ow2, const float* __restrict__ ow3,
                          const float* __restrict__ wd,
                          short* __restrict__ wb0, short* __restrict__ wb1,
                          short* __restrict__ wb2, short* __restrict__ wb3,
                          short* __restrict__ wbd) {
    int i = blockIdx.x * 256 + threadIdx.x;
    const int z1 = 4 * 388 * 224, z2 = 4 * 388 * 64;
    if (i < z1 + 2 * z2) {
        short* p; int C;
        if (i < z1) { p = xpad1; C = 224; }
        else if (i < z1 + z2) { p = hpa; C = 64; i -= z1; }
        else { p = hpb; C = 64; i -= z1 + z2; }
        int c = i % C;
        int r = i / C;
        int b = r / 388, pid = r - b * 388;
        int row, col;
        if (pid < 98)       { row = 0;  col = pid; }
        else if (pid < 196) { row = 97; col = pid - 98; }
        else if (pid < 292) { row = pid - 196 + 1; col = 0; }
        else                { row = pid - 292 + 1; col = 97; }
        p[((size_t)b * PHW + row * 98 + col) * C + c] = 0;
        return;
    }
    i -= z1 + 2 * z2;
    const int zr = 4 * 16 * 388 * 8;
    if (i < zr) {
        int c8 = i & 7;
        int r = i >> 3;
        int pid = r % 388;
        int bg = r / 388;
        int row, col;
        if (pid < 98)       { row = 0;  col = pid; }
        else if (pid < 196) { row = 97; col = pid - 98; }
        else if (pid < 292) { row = pid - 196 + 1; col = 0; }
        else                { row = pid - 292 + 1; col = 97; }
        xdp[((size_t)bg * PHW + row * 98 + col) * 8 + c8] = 0;
        return;
    }
    i -= zr;
    const int n0 = 64 * 9 * 224, n1 = 64 * 9 * 64, n3 = 448 * 9 * 64, nd = 64 * 1152;
    if (i < n0) {
        int co = i / (9 * 224); int r = i - co * (9 * 224);
        int tap = r / 224, ci = r - tap * 224;
        wb0[i] = f2bf(ci < 196 ? ow0[(co * 196 + ci) * 9 + tap] : 0.f);
        return;
    }
    i -= n0;
    if (i < n1) {
        int co = i / (9 * 64); int r = i - co * (9 * 64);
        int tap = r / 64, ci = r - tap * 64;
        wb1[i] = f2bf(ow1[(co * 64 + ci) * 9 + tap]);
        return;
    }
    i -= n1;
    if (i < n1) {
        int co = i / (9 * 64); int r = i - co * (9 * 64);
        int tap = r / 64, ci = r - tap * 64;
        wb2[i] = f2bf(ow2[(co * 64 + ci) * 9 + tap]);
        return;
    }
    i -= n1;
    if (i < n3) {
        int co = i / (9 * 64); int r = i - co * (9 * 64);
        int tap = r / 64, ci = r - tap * 64;
        wb3[i] = f2bf(co < 432 ? ow3[(co * 64 + ci) * 9 + tap] : 0.f);
        return;
    }
    i -= n3;
    if (i < nd) {
        int co = i / 1152, kd = i - co * 1152;
        int gt = kd >> 3, c = kd & 7;
        int g = gt / 9, tap = gt - g * 9;
        wbd[i] = f2bf(wd[(co * 128 + g * 8 + c) * 9 + tap]);
    }
}

// ---------------------------------------------------------------------------
// Fused packers. y<7: concat->xpad1. y>=7: x->xdp padded group-planar.
__global__ void pack_all(const float* __restrict__ extra,
                         const float* __restrict__ f1,
                         const float* __restrict__ f2,
                         const float* __restrict__ x,
                         short* __restrict__ xp,
                         short* __restrict__ xdp) {
    __shared__ float t[32][33];
    const int tid = threadIdx.x, tx = tid & 31, ty = tid >> 5;
    const int pt = blockIdx.x, b = blockIdx.z;
    if (blockIdx.y < 7) {
        const int ct = blockIdx.y;
#pragma unroll
        for (int j = 0; j < 4; ++j) {
            int ch = ct * 32 + ty + j * 8;
            int p = pt * 32 + tx;
            float v = 0.f;
            if (ch < 192)      v = extra[(b * 192 + ch) * HW + p];
            else if (ch < 194) v = f1[(b * 2 + ch - 192) * HW + p];
            else if (ch < 196) v = f2[(b * 2 + ch - 194) * HW + p];
            t[ty + j * 8][tx] = v;
        }
        __syncthreads();
#pragma unroll
        for (int j = 0; j < 4; ++j) {
            int pr = ty + j * 8;
            int p = pt * 32 + pr;
            int r = p / 96, c = p - r * 96;
            xp[((size_t)b * PHW + (r + 1) * 98 + (c + 1)) * 224 + ct * 32 + tx] =
                f2bf(t[tx][pr]);
        }
    } else {
        const int ct = blockIdx.y - 7;
#pragma unroll
        for (int j = 0; j < 4; ++j) {
            int ch = ct * 32 + ty + j * 8;
            t[ty + j * 8][tx] = x[((size_t)b * 128 + ch) * HW + pt * 32 + tx];
        }
        __syncthreads();
        if (tid < 128) {
            int oct = tid >> 5, p = tid & 31;
            int g = ct * 4 + oct;
            int pix = pt * 32 + p;
            int r = pix / 96, c = pix - r * 96;
            bh8 v;
#pragma unroll
            for (int cc = 0; cc < 8; ++cc) v[cc] = f2bf(t[oct * 8 + cc][p]);
            *(bh8*)&xdp[(((size_t)b * 16 + g) * PHW + (r + 1) * 98 + (c + 1)) * 8] = v;
        }
    }
}

// ---------------------------------------------------------------------------
// conv1-3 (r8 structure, untouched): block = 4 waves x (16px x 64co),
// weight chunk staged in LDS per 32-cin chunk, B-frags direct global loads.
// ---------------------------------------------------------------------------
template<int CINP, int KCH>
__launch_bounds__(256)
__global__ void conv_mfma(const short* __restrict__ xp,
                          const short* __restrict__ wb,
                          const float* __restrict__ bias,
                          short* __restrict__ o1) {
    __shared__ __attribute__((aligned(16))) short smA[9 * 64 * 32];
    const int tid = threadIdx.x;
    const int lane = tid & 63, wv = tid >> 6;
    const int q = lane >> 4, l15 = lane & 15;
    const int b = blockIdx.y;
    const int pix0 = blockIdx.x * 64 + wv * 16;
    const int soh = pix0 / 96, sow = pix0 - (pix0 / 96) * 96;

    const short* bp = xp + ((size_t)b * PHW + soh * 98 + sow + l15) * CINP + q * 8;

    const int sco = tid >> 2, sqq = tid & 3;
    const short* wsrc = wb + (size_t)sco * (9 * CINP) + sqq * 8;

    f32x4 acc[4];
#pragma unroll
    for (int t = 0; t < 4; ++t) acc[t] = (f32x4){0.f, 0.f, 0.f, 0.f};

    for (int p = 0; p < KCH; ++p) {
        __syncthreads();
        bh8 wtmp[9];
#pragma unroll
        for (int tap = 0; tap < 9; ++tap)
            wtmp[tap] = *(const bh8*)(wsrc + tap * CINP + p * 32);
#pragma unroll
        for (int tap = 0; tap < 9; ++tap)
            *(bh8*)&smA[tap * 2048 + sco * 32 + sqq * 8] = wtmp[tap];
        __syncthreads();
#pragma unroll
        for (int tap = 0; tap < 9; ++tap) {
            const int ky = tap / 3, kx = tap - (tap / 3) * 3;
            bh8 bf = *(const bh8*)(bp + (ky * 98 + kx) * CINP + p * 32);
#pragma unroll
            for (int t = 0; t < 4; ++t) {
                bh8 af = *(const bh8*)&smA[tap * 2048 + (t * 16 + l15) * 32 + q * 8];
                acc[t] = __builtin_amdgcn_mfma_f32_16x16x32_bf16(af, bf, acc[t], 0, 0, 0);
            }
        }
    }

    size_t base = ((size_t)b * PHW + (soh + 1) * 98 + sow + l15 + 1) * 64;
#pragma unroll
    for (int t = 0; t < 4; ++t) {
        bh4 v4;
#pragma unroll
        for (int r = 0; r < 4; ++r) {
            int co = t * 16 + q * 4 + r;
            float v = acc[t][r] + bias[co];
            v = (v >= 0.f) ? v : 0.1f * v;
            v4[r] = f2bf(v);
        }
        *(bh4*)(o1 + base + t * 16 + q * 4) = v4;
    }
}

// ---------------------------------------------------------------------------
// conv4 (r12 structure): z=7 co-split, 3 phases, async global_load_lds A
// staging (24 KB), 6 barriers, barrier-free 6-chunk compute runs.
// Epilogue now stores offsets as fp16 half2 (4 B per (dy,dx)).
// ---------------------------------------------------------------------------
__launch_bounds__(256, 2)
__global__ void conv4_gemm(const short* __restrict__ xp,
                           const short* __restrict__ wb,
                           const float* __restrict__ bias,
                           _Float16* __restrict__ offp,
                           short* __restrict__ maskb,
                           const float* __restrict__ flow1,
                           const float* __restrict__ flow2) {
    __shared__ __attribute__((aligned(16))) short smA[6 * 64 * 32];   // 24 KB
    const int tid = threadIdx.x;
    const int lane = tid & 63, wv = tid >> 6;
    const int q = lane >> 4, l15 = lane & 15;
    const int b = blockIdx.y;
    const int cob = blockIdx.z * 64;
    const int pixw = blockIdx.x * 192 + wv * 48;

    const short* bp[3];
#pragma unroll
    for (int s = 0; s < 3; ++s) {
        int pixs = pixw + s * 16;
        int soh = pixs / 96, sow = pixs - (pixs / 96) * 96;
        bp[s] = xp + ((size_t)b * PHW + soh * 98 + sow + l15) * 64 + q * 8;
    }

    const short* asrc = wb + (size_t)(cob + wv * 16 + (lane >> 2)) * 576 + (lane & 3) * 8;
    short* sdst = &smA[wv * 512];

    f32x4 acc[4][3];
#pragma unroll
    for (int cf = 0; cf < 4; ++cf)
#pragma unroll
        for (int s = 0; s < 3; ++s) acc[cf][s] = (f32x4){0.f, 0.f, 0.f, 0.f};

#pragma unroll
    for (int ph = 0; ph < 3; ++ph) {
        __syncthreads();
#pragma unroll
        for (int c6 = 0; c6 < 6; ++c6) {
            const int tap = ph * 3 + (c6 >> 1), kc = c6 & 1;
            async_lds16(asrc + tap * 64 + kc * 32, sdst + c6 * 2048);
        }
        __syncthreads();
#pragma unroll
        for (int c6 = 0; c6 < 6; ++c6) {
            const int tap = ph * 3 + (c6 >> 1), kc = c6 & 1;
            const int ky = tap / 3, kx = tap - (tap / 3) * 3;
            bh8 bf[3], af[4];
#pragma unroll
            for (int s = 0; s < 3; ++s)
                bf[s] = *(const bh8*)(bp[s] + (ky * 98 + kx) * 64 + kc * 32);
#pragma unroll
            for (int cf = 0; cf < 4; ++cf)
                af[cf] = *(const bh8*)&smA[c6 * 2048 + (cf * 16 + l15) * 32 + q * 8];
#pragma unroll
            for (int cf = 0; cf < 4; ++cf)
#pragma unroll
                for (int s = 0; s < 3; ++s)
                    acc[cf][s] = __builtin_amdgcn_mfma_f32_16x16x32_bf16(
                        af[cf], bf[s], acc[cf][s], 0, 0, 0);
        }
    }

#pragma unroll
    for (int s = 0; s < 3; ++s) {
        int pix = pixw + s * 16 + l15;
#pragma unroll
        for (int cf = 0; cf < 4; ++cf) {
            int cb0 = cob + cf * 16 + q * 4;
            if (cb0 < 288) {
                const float* fl = (cb0 < 144) ? flow1 : flow2;
                float fe = fl[(b * 2 + 1) * HW + pix];
                float fo = fl[(b * 2) * HW + pix];
                float t0 = 10.f * tanhf(acc[cf][s][0] + bias[cb0 + 0]) + fe;
                float t1 = 10.f * tanhf(acc[cf][s][1] + bias[cb0 + 1]) + fo;
                float t2 = 10.f * tanhf(acc[cf][s][2] + bias[cb0 + 2]) + fe;
                float t3 = 10.f * tanhf(acc[cf][s][3] + bias[cb0 + 3]) + fo;
                size_t p0 = ((size_t)b * 144 + (cb0 >> 1)) * HW + pix;   // half2 units
                *(h16x2*)&offp[p0 * 2] = (h16x2){(_Float16)t0, (_Float16)t1};
                *(h16x2*)&offp[(p0 + HW) * 2] = (h16x2){(_Float16)t2, (_Float16)t3};
            } else {
#pragma unroll
                for (int r = 0; r < 4; ++r) {
                    int chn = cb0 + r;
                    if (chn < 432) {
                        float v = acc[cf][s][r] + bias[chn];
                        maskb[((size_t)b * 144 + (chn - 288)) * HW + pix] =
                            f2bf(1.f / (1.f + expf(-v)));
                    }
                }
            }
        }
    }
}

// ---------------------------------------------------------------------------
// Deform (r8 exact structure + fp16 offset reads): padded zero-ring xdp,
// packed bf16 math, precomputed pointers, XCD-swizzled blocks.
// ---------------------------------------------------------------------------
__launch_bounds__(256)
__global__ void deform_mfma(const short* __restrict__ xdp,
                            const _Float16* __restrict__ offp,
                            const short* __restrict__ maskb,
                            const short* __restrict__ wbd,
                            const float* __restrict__ bias,
                            float* __restrict__ out) {
    __shared__ float red[4][1024];
    const int tid = threadIdx.x;
    const int lane = tid & 63, wv = tid >> 6;
    const int q = lane >> 4, l15 = lane & 15;
    const int blk = blockIdx.x;
    const int xs = blk & 7, idx = blk >> 3;
    const int b = xs >> 1;
    const int pix0 = ((xs & 1) * 288 + idx) * 16;
    const int pix = pix0 + l15;
    const int h = pix / 96, w = pix - (pix / 96) * 96;

    const _Float16* opp = offp + ((size_t)b * 144 * HW + pix) * 2;
    const short* mp = maskb + (size_t)b * 144 * HW + pix;
    const short* xb = xdp + (size_t)b * 16 * PHW * 8;
    const short* ap = wbd + (size_t)l15 * 1152 + wv * 288 + q * 8;

    f32x2 dxy[9];
    float mk[9];
#pragma unroll
    for (int i = 0; i < 9; ++i) {
        const int gt = wv * 36 + i * 4 + q;
        h16x2 v = *(const h16x2*)(opp + (size_t)gt * HW * 2);
        dxy[i] = (f32x2){(float)v[0], (float)v[1]};
        mk[i] = bf2f(mp[(size_t)gt * HW]);
    }

    const short* cp[9];
    f32x4 ww[9];
#pragma unroll
    for (int i = 0; i < 9; ++i) {
        const int gt = wv * 36 + i * 4 + q;
        const int g = gt / 9, tap = gt - (gt / 9) * 9;
        float py = dxy[i][0] + (float)(tap / 3) + (float)h - 1.f;
        float px = dxy[i][1] + (float)(tap - (tap / 3) * 3) + (float)w - 1.f;
        py = fminf(fmaxf(py, -1.f), 96.f);
        px = fminf(fmaxf(px, -1.f), 96.f);
        float y0f = floorf(py), x0f = floorf(px);
        float wy1 = py - y0f, wx1 = px - x0f;
        float wy0 = 1.f - wy1, wx0 = 1.f - wx1;
        int yp = (int)y0f + 1, xp = (int)x0f + 1;
        cp[i] = xb + ((size_t)g * PHW + yp * 98 + xp) * 8;
        float m = mk[i];
        ww[i] = (f32x4){wy0 * wx0 * m, wy0 * wx1 * m, wy1 * wx0 * m, wy1 * wx1 * m};
    }

    f32x4 acc[4];
#pragma unroll
    for (int t = 0; t < 4; ++t) acc[t] = (f32x4){0.f, 0.f, 0.f, 0.f};

#pragma unroll
    for (int i = 0; i < 9; ++i) {
        bh8i c00, c01, c10, c11;
        c00.v = *(const bh8*)(cp[i]);
        c01.v = *(const bh8*)(cp[i] + 8);
        c10.v = *(const bh8*)(cp[i] + 98 * 8);
        c11.v = *(const bh8*)(cp[i] + 99 * 8);
        const float w00 = ww[i][0], w01 = ww[i][1], w10 = ww[i][2], w11 = ww[i][3];
        bh8i bf;
#pragma unroll
        for (int k = 0; k < 4; ++k) {
            unsigned u00 = (unsigned)c00.i[k], u01 = (unsigned)c01.i[k];
            unsigned u10 = (unsigned)c10.i[k], u11 = (unsigned)c11.i[k];
            float lo = w00 * lo_bf(u00) + w01 * lo_bf(u01)
                     + w10 * lo_bf(u10) + w11 * lo_bf(u11);
            float hi = w00 * hi_bf(u00) + w01 * hi_bf(u01)
                     + w10 * hi_bf(u10) + w11 * hi_bf(u11);
            bf.i[k] = (int)pack_bf2(lo, hi);
        }
#pragma unroll
        for (int t = 0; t < 4; ++t) {
            bh8 af = *(const bh8*)(ap + (size_t)t * 16 * 1152 + i * 32);
            acc[t] = __builtin_amdgcn_mfma_f32_16x16x32_bf16(af, bf.v, acc[t], 0, 0, 0);
        }
    }

#pragma unroll
    for (int t = 0; t < 4; ++t)
#pragma unroll
        for (int r = 0; r < 4; ++r)
            red[wv][(t * 16 + q * 4 + r) * 16 + l15] = acc[t][r];
    __syncthreads();
    for (int e = tid; e < 1024; e += 256) {
        int co = e >> 4, pl = e & 15;
        float v = red[0][e] + red[1][e] + red[2][e] + red[3][e] + bias[co];
        out[((size_t)b * 64 + co) * HW + pix0 + pl] = v;
    }
}

// ---------------------------------------------------------------------------
extern "C" void kernel_launch(void* const* d_in, const int* in_sizes, int n_in,
                              void* d_out, int out_size, void* d_ws, size_t ws_size,
                              hipStream_t stream) {
    const float* x      = (const float*)d_in[0];
    const float* extra  = (const float*)d_in[1];
    const float* flow1  = (const float*)d_in[2];
    const float* flow2  = (const float*)d_in[3];
    const float* weight = (const float*)d_in[4];
    const float* bias   = (const float*)d_in[5];
    const float* ow0    = (const float*)d_in[6];
    const float* ob0    = (const float*)d_in[7];
    const float* ow1    = (const float*)d_in[8];
    const float* ob1    = (const float*)d_in[9];
    const float* ow2    = (const float*)d_in[10];
    const float* ob2    = (const float*)d_in[11];
    const float* ow3    = (const float*)d_in[12];
    const float* ob3    = (const float*)d_in[13];
    float* out = (float*)d_out;

    char* wsb = (char*)d_ws;
    short* xpad1 = (short*)wsb;       wsb += (size_t)4 * PHW * 224 * 2;
    short* hpa   = (short*)wsb;       wsb += (size_t)4 * PHW * 64 * 2;
    short* hpb   = (short*)wsb;       wsb += (size_t)4 * PHW * 64 * 2;
    _Float16* offpair = (_Float16*)wsb; wsb += (size_t)4 * 144 * HW * 2 * 2;
    short* maskbuf = (short*)wsb;     wsb += (size_t)4 * 144 * HW * 2;
    short* xdp     = (short*)wsb;     wsb += (size_t)4 * 16 * PHW * 8 * 2 + 32;
    short* wb0     = (short*)wsb;     wsb += 64 * 9 * 224 * 2;
    short* wb1     = (short*)wsb;     wsb += 64 * 9 * 64 * 2;
    short* wb2     = (short*)wsb;     wsb += 64 * 9 * 64 * 2;
    short* wb3     = (short*)wsb;     wsb += 448 * 9 * 64 * 2;
    short* wbd     = (short*)wsb;

    const int prep_total = 546304 + 198656 + 534528;
    prep_misc<<<dim3((prep_total + 255) / 256), 256, 0, stream>>>(
        xpad1, hpa, hpb, xdp, ow0, ow1, ow2, ow3, weight,
        wb0, wb1, wb2, wb3, wbd);
    pack_all<<<dim3(288, 11, 4), 256, 0, stream>>>(extra, flow1, flow2, x, xpad1, xdp);

    conv_mfma<224, 7><<<dim3(144, 4), 256, 0, stream>>>(xpad1, wb0, ob0, hpa);
    conv_mfma<64, 2><<<dim3(144, 4), 256, 0, stream>>>(hpa, wb1, ob1, hpb);
    conv_mfma<64, 2><<<dim3(144, 4), 256, 0, stream>>>(hpb, wb2, ob2, hpa);
    conv4_gemm<<<dim3(48, 4, 7), 256, 0, stream>>>(hpa, wb3, ob3, offpair,
                                                   maskbuf, flow1, flow2);
    deform_mfma<<<dim3(2304), 256, 0, stream>>>(xdp, offpair, maskbuf, wbd, bias, out);
}